// Round 9
// baseline (33.649 us; speedup 1.0000x reference)
//
#include <hip/hip_runtime.h>
#include <cstdint>

#define IN_F 128
#define OUT_F 128
#define NPB 8        // nodes per block
#define WAVES 16
#define THREADS 1024
#define TROWS 64     // rows per LDS tile (32 KB f32)
#define NEG_BIG -1e30f

__device__ __forceinline__ void gload16(const void* g, void* l) {
    __builtin_amdgcn_global_load_lds(
        (const __attribute__((address_space(1))) void*)g,
        (__attribute__((address_space(3))) void*)l, 16, 0, 0);
}

__global__ __launch_bounds__(THREADS, 4) void sage_kernel(
    const float* __restrict__ h, const int* __restrict__ adj,
    const float* __restrict__ Ws, const float* __restrict__ bs,
    const float* __restrict__ Wn, const float* __restrict__ bn,
    const float* __restrict__ gamma, const float* __restrict__ beta,
    float* __restrict__ out, int N)
{
    // 64 KB time-shared: [tileA 32K | tileB 32K] -> scanp 64K -> gemmp 32K
    __shared__ __align__(16) char spraw[65536];
    __shared__ float h_self[NPB][IN_F];          // 4 KB
    __shared__ float agg_s[NPB][IN_F];           // 4 KB
    __shared__ unsigned anyw_s[WAVES];

    float* const tileA = (float*)spraw;
    float* const tileB = (float*)(spraw + 32768);
    auto scanp = (float2 (*)[NPB][64])spraw;     // [WAVES][NPB][64]
    auto gemmp = (float (*)[NPB][OUT_F])spraw;   // [8][NPB][128]

    const int t    = threadIdx.x;
    const int w    = t >> 6;
    const int lane = t & 63;

    const int base = blockIdx.x * NPB;
    const int b    = base / N;
    const int i0   = base - b * N;

    const float* hb   = h   + (size_t)b * N * IN_F;
    const int*   adjb = adj + (size_t)b * N * N;
    const int    T    = N / TROWS;               // 16 (N=1024)

    // ---- masks in SGPRs: wave w owns rows {tt*64 + w*4 + q}, bit index = tt*4+q ----
    const int rowL = ((lane >> 2) * TROWS) + (w << 2) + (lane & 3);
    unsigned long long m[NPB];
    unsigned anybits = 0;
    #pragma unroll
    for (int n = 0; n < NPB; ++n) {
        const int i_n = i0 + n;
        m[n] = __ballot(adjb[(size_t)i_n * N + rowL] != 0 && rowL != i_n);
        anybits |= (m[n] != 0ull ? 1u : 0u) << n;
    }

    float ax[NPB], ay[NPB];
    #pragma unroll
    for (int n = 0; n < NPB; ++n) { ax[n] = NEG_BIG; ay[n] = NEG_BIG; }

    // ---- async stage: tile -> LDS, 2x 16B per lane, linear layout ----
    auto stage = [&](float* dst, int tile) {
        const char* g = (const char*)(hb + (size_t)tile * TROWS * IN_F)
                        + w * 1024 + lane * 16;
        char* l = (char*)dst + w * 1024;         // wave-uniform base + lane*16 (HW)
        gload16(g, l);
        gload16(g + 16384, l + 16384);
    };

    stage(tileA, 0);
    const float PINF = __builtin_inff();

    // ---- double-buffered scan: DMA(t+1) overlaps compute(t) ----
    for (int tt = 0; tt < T; ++tt) {
        __syncthreads();   // vmcnt(0) drain: buf[tt] ready; prev buf reads done
        if (tt + 1 < T) stage((tt & 1) ? tileA : tileB, tt + 1);
        const float* buf = (tt & 1) ? tileB : tileA;
        const float* rb  = buf + (w * 4) * IN_F + 2 * lane;
        #pragma unroll
        for (int pp = 0; pp < 2; ++pp) {
            const float2 v0 = *(const float2*)(rb + (2 * pp)     * IN_F); // offset imm
            const float2 v1 = *(const float2*)(rb + (2 * pp + 1) * IN_F);
            const int sh = tt * 4 + 2 * pp;
            #pragma unroll
            for (int n = 0; n < NPB; ++n) {
                const float c0 = ((m[n] >> sh)       & 1ull) ? PINF : -PINF; // s_cselect
                const float c1 = ((m[n] >> (sh + 1)) & 1ull) ? PINF : -PINF;
                ax[n] = fmaxf(fmaxf(fminf(v0.x, c0), fminf(v1.x, c1)), ax[n]); // v_max3
                ay[n] = fmaxf(fmaxf(fminf(v0.y, c0), fminf(v1.y, c1)), ay[n]);
            }
        }
    }

    __syncthreads();   // all tile reads done -> scanp may overwrite tiles
    #pragma unroll
    for (int n = 0; n < NPB; ++n) scanp[w][n][lane] = make_float2(ax[n], ay[n]);
    if (lane == 0) anyw_s[w] = anybits;
    __syncthreads();

    // ---- combine partials (waves 0-7) / stage h_self (waves 8-15) ----
    if (w < NPB) {
        float rx = NEG_BIG, ry = NEG_BIG;
        #pragma unroll
        for (int wp = 0; wp < WAVES; ++wp) {
            const float2 p = scanp[wp][w][lane];
            rx = fmaxf(rx, p.x);
            ry = fmaxf(ry, p.y);
        }
        unsigned anyall = 0;
        #pragma unroll
        for (int wp = 0; wp < WAVES; ++wp) anyall |= anyw_s[wp];
        const float2 hs = *(const float2*)&hb[(size_t)(i0 + w) * IN_F + 2 * lane];
        if (!((anyall >> w) & 1u)) { rx = hs.x; ry = hs.y; }
        *(float2*)&agg_s[w][2 * lane] = make_float2(rx, ry);
    } else {
        const int n2 = w - NPB;
        const float2 hs = *(const float2*)&hb[(size_t)(i0 + n2) * IN_F + 2 * lane];
        *(float2*)&h_self[n2][2 * lane] = hs;
    }
    __syncthreads();   // agg ready; scanp consumed -> gemmp may overwrite

    // ---- GEMMs: thread (o = t&127, fc = t>>7) handles ALL 8 nodes ----
    {
        const int o  = t & (OUT_F - 1);
        const int fc = t >> 7;                   // 0..7, wave-uniform
        float acc[NPB];
        #pragma unroll
        for (int n = 0; n < NPB; ++n) acc[n] = 0.0f;

        const int f0 = fc * (IN_F / 8);          // 16 f's per chunk
        #pragma unroll 4
        for (int ff = 0; ff < IN_F / 8; ++ff) {
            const int f = f0 + ff;
            const float ws = Ws[f * OUT_F + o];
            const float wn = Wn[f * OUT_F + o];
            #pragma unroll
            for (int n = 0; n < NPB; ++n) {
                acc[n] = fmaf(h_self[n][f], ws, acc[n]);  // uniform LDS broadcast
                acc[n] = fmaf(agg_s[n][f],  wn, acc[n]);
            }
        }
        #pragma unroll
        for (int n = 0; n < NPB; ++n) gemmp[fc][n][o] = acc[n];
    }
    __syncthreads();

    // ---- merged reduce + bias + LayerNorm + ReLU (waves 0-7, node w) ----
    if (w < NPB) {
        float x0 = bs[lane]      + bn[lane];
        float x1 = bs[lane + 64] + bn[lane + 64];
        #pragma unroll
        for (int fcc = 0; fcc < 8; ++fcc) {
            x0 += gemmp[fcc][w][lane];
            x1 += gemmp[fcc][w][lane + 64];
        }
        float s  = x0 + x1;
        float s2 = x0 * x0 + x1 * x1;
        #pragma unroll
        for (int d = 32; d >= 1; d >>= 1) {
            s  += __shfl_xor(s, d, 64);
            s2 += __shfl_xor(s2, d, 64);
        }
        const float mu  = s * (1.0f / OUT_F);
        const float var = s2 * (1.0f / OUT_F) - mu * mu;
        const float rs  = rsqrtf(var + 1e-5f);

        float* orow = out + (size_t)(base + w) * OUT_F;
        const float r0 = (x0 - mu) * rs * gamma[lane]      + beta[lane];
        const float r1 = (x1 - mu) * rs * gamma[lane + 64] + beta[lane + 64];
        orow[lane]      = fmaxf(r0, 0.0f);
        orow[lane + 64] = fmaxf(r1, 0.0f);
    }
}

extern "C" void kernel_launch(void* const* d_in, const int* in_sizes, int n_in,
                              void* d_out, int out_size, void* d_ws, size_t ws_size,
                              hipStream_t stream) {
    const float* h     = (const float*)d_in[0];
    const int*   adj   = (const int*)d_in[1];
    const float* Ws    = (const float*)d_in[2];
    const float* bs    = (const float*)d_in[3];
    const float* Wn    = (const float*)d_in[4];
    const float* bn    = (const float*)d_in[5];
    const float* gamma = (const float*)d_in[6];
    const float* beta  = (const float*)d_in[7];
    float* out = (float*)d_out;

    const long long bn_nodes = in_sizes[0] / IN_F;          // B*N
    const int N = (int)((long long)in_sizes[1] / bn_nodes); // adj is B*N*N
    const int grid = (int)(bn_nodes / NPB);

    hipLaunchKernelGGL(sage_kernel, dim3(grid), dim3(THREADS), 0, stream,
                       h, adj, Ws, bs, Wn, bn, gamma, beta, out, N);
}

// Round 10
// 28.192 us; speedup vs baseline: 1.1936x; 1.1936x over previous
//
#include <hip/hip_runtime.h>
#include <cstdint>

#define IN_F 128
#define OUT_F 128
#define NPB 8        // nodes per block
#define WAVES 16
#define THREADS 1024
#define NEG_BIG -1e30f

// TN = compile-time N (1024), or 0 for runtime-generic fallback.
template<int TN>
__global__ __launch_bounds__(THREADS, 4) void sage_kernel(
    const float* __restrict__ h, const int* __restrict__ adj,
    const float* __restrict__ Ws, const float* __restrict__ bs,
    const float* __restrict__ Wn, const float* __restrict__ bn,
    const float* __restrict__ gamma, const float* __restrict__ beta,
    float* __restrict__ out, int Nrt)
{
    const int N = TN ? TN : Nrt;
    const int STRIP = N / WAVES;                 // 64 when N=1024

    // 64 KB time-shared: scanp (f32x2 partials) -> gemmp
    __shared__ __align__(16) char spraw[WAVES * NPB * 64 * 8];
    auto scanp = (float2 (*)[NPB][64])spraw;     // [WAVES][NPB][64]
    auto gemmp = (float (*)[NPB][OUT_F])spraw;   // [8][NPB][128] (32 KB)

    __shared__ unsigned anyw_s[WAVES];
    __shared__ float h_self[NPB][IN_F];          // 4 KB
    __shared__ float agg_s[NPB][IN_F];           // 4 KB

    const int t    = threadIdx.x;
    const int w    = t >> 6;
    const int lane = t & 63;

    const int base = blockIdx.x * NPB;
    const int b    = base / N;
    const int i0   = base - b * N;

    const float* hb   = h   + (size_t)b * N * IN_F;
    const int*   adjb = adj + (size_t)b * N * N;
    const int jbase   = w * STRIP;

    // ---- one u64 mask per node over this wave's 64-column strip ----
    unsigned long long m[NPB];
    unsigned anybits = 0;
    #pragma unroll
    for (int n = 0; n < NPB; ++n) {
        const int i_n = i0 + n;
        const int j   = jbase + lane;
        m[n] = __ballot(adjb[(size_t)i_n * N + j] != 0 && j != i_n);
        anybits |= (m[n] != 0ull ? 1u : 0u) << n;
    }

    float ax[NPB], ay[NPB];
    #pragma unroll
    for (int n = 0; n < NPB; ++n) { ax[n] = NEG_BIG; ay[n] = NEG_BIG; }

    const float PINF = __builtin_inff();
    const float* hrow = hb + (size_t)jbase * IN_F + 2 * lane;

    if constexpr (TN == 1024) {
        // ---- fully unrolled scan: literal shifts, imm-offset loads ----
        #pragma unroll
        for (int g = 0; g < 8; ++g) {
            const float* p = hrow + g * 8 * IN_F;   // one base bump / 8 rows
            float2 v[8];
            #pragma unroll
            for (int r = 0; r < 8; ++r)
                v[r] = *(const float2*)(p + r * IN_F);   // imm offsets r*512B
            #pragma unroll
            for (int pr = 0; pr < 4; ++pr) {
                #pragma unroll
                for (int n = 0; n < NPB; ++n) {
                    const float c0 = ((m[n] >> (g * 8 + 2 * pr))     & 1ull) ? PINF : -PINF;
                    const float c1 = ((m[n] >> (g * 8 + 2 * pr + 1)) & 1ull) ? PINF : -PINF;
                    ax[n] = fmaxf(fmaxf(fminf(v[2 * pr].x, c0), fminf(v[2 * pr + 1].x, c1)), ax[n]);
                    ay[n] = fmaxf(fmaxf(fminf(v[2 * pr].y, c0), fminf(v[2 * pr + 1].y, c1)), ay[n]);
                }
            }
        }
    } else {
        for (int k = 0; k < STRIP; ++k) {
            const float2 v = *(const float2*)(hrow + (size_t)k * IN_F);
            #pragma unroll
            for (int n = 0; n < NPB; ++n) {
                const float c = ((m[n] >> k) & 1ull) ? PINF : -PINF;
                ax[n] = fmaxf(ax[n], fminf(v.x, c));
                ay[n] = fmaxf(ay[n], fminf(v.y, c));
            }
        }
    }

    #pragma unroll
    for (int n = 0; n < NPB; ++n) scanp[w][n][lane] = make_float2(ax[n], ay[n]);
    if (lane == 0) anyw_s[w] = anybits;
    __syncthreads();

    // ---- combine partials (waves 0-7) / stage h_self (waves 8-15) ----
    if (w < NPB) {
        float rx = NEG_BIG, ry = NEG_BIG;
        #pragma unroll
        for (int wp = 0; wp < WAVES; ++wp) {
            const float2 p = scanp[wp][w][lane];
            rx = fmaxf(rx, p.x);
            ry = fmaxf(ry, p.y);
        }
        unsigned anyall = 0;
        #pragma unroll
        for (int wp = 0; wp < WAVES; ++wp) anyall |= anyw_s[wp];
        const float2 hs = *(const float2*)&hb[(size_t)(i0 + w) * IN_F + 2 * lane];
        if (!((anyall >> w) & 1u)) { rx = hs.x; ry = hs.y; }
        *(float2*)&agg_s[w][2 * lane] = make_float2(rx, ry);
    } else {
        const int n2 = w - NPB;
        const float2 hs = *(const float2*)&hb[(size_t)(i0 + n2) * IN_F + 2 * lane];
        *(float2*)&h_self[n2][2 * lane] = hs;
    }
    __syncthreads();   // scanp consumed -> gemmp may overwrite

    // ---- GEMMs: thread (o = t&127, fc = t>>7) handles ALL 8 nodes ----
    {
        const int o  = t & (OUT_F - 1);
        const int fc = t >> 7;                   // 0..7, wave-uniform
        float acc[NPB];
        #pragma unroll
        for (int n = 0; n < NPB; ++n) acc[n] = 0.0f;

        const int f0 = fc * (IN_F / 8);          // 16 f's per chunk
        #pragma unroll
        for (int ff = 0; ff < IN_F / 8; ++ff) {
            const int f = f0 + ff;
            const float ws = Ws[f * OUT_F + o];
            const float wn = Wn[f * OUT_F + o];
            #pragma unroll
            for (int n = 0; n < NPB; ++n) {
                acc[n] = fmaf(h_self[n][f], ws, acc[n]);  // uniform LDS broadcast
                acc[n] = fmaf(agg_s[n][f],  wn, acc[n]);
            }
        }
        #pragma unroll
        for (int n = 0; n < NPB; ++n) gemmp[fc][n][o] = acc[n];
    }
    __syncthreads();

    // ---- merged reduce + bias + LayerNorm + ReLU (waves 0-7, node w) ----
    if (w < NPB) {
        float x0 = bs[lane]      + bn[lane];
        float x1 = bs[lane + 64] + bn[lane + 64];
        #pragma unroll
        for (int fcc = 0; fcc < 8; ++fcc) {
            x0 += gemmp[fcc][w][lane];
            x1 += gemmp[fcc][w][lane + 64];
        }
        float s  = x0 + x1;
        float s2 = x0 * x0 + x1 * x1;
        #pragma unroll
        for (int d = 32; d >= 1; d >>= 1) {
            s  += __shfl_xor(s, d, 64);
            s2 += __shfl_xor(s2, d, 64);
        }
        const float mu  = s * (1.0f / OUT_F);
        const float var = s2 * (1.0f / OUT_F) - mu * mu;
        const float rs  = rsqrtf(var + 1e-5f);

        float* orow = out + (size_t)(base + w) * OUT_F;
        const float r0 = (x0 - mu) * rs * gamma[lane]      + beta[lane];
        const float r1 = (x1 - mu) * rs * gamma[lane + 64] + beta[lane + 64];
        orow[lane]      = fmaxf(r0, 0.0f);
        orow[lane + 64] = fmaxf(r1, 0.0f);
    }
}

extern "C" void kernel_launch(void* const* d_in, const int* in_sizes, int n_in,
                              void* d_out, int out_size, void* d_ws, size_t ws_size,
                              hipStream_t stream) {
    const float* h     = (const float*)d_in[0];
    const int*   adj   = (const int*)d_in[1];
    const float* Ws    = (const float*)d_in[2];
    const float* bs    = (const float*)d_in[3];
    const float* Wn    = (const float*)d_in[4];
    const float* bn    = (const float*)d_in[5];
    const float* gamma = (const float*)d_in[6];
    const float* beta  = (const float*)d_in[7];
    float* out = (float*)d_out;

    const long long bn_nodes = in_sizes[0] / IN_F;          // B*N
    const int N = (int)((long long)in_sizes[1] / bn_nodes); // adj is B*N*N
    const int grid = (int)(bn_nodes / NPB);

    if (N == 1024) {
        hipLaunchKernelGGL(sage_kernel<1024>, dim3(grid), dim3(THREADS), 0, stream,
                           h, adj, Ws, bs, Wn, bn, gamma, beta, out, N);
    } else {
        hipLaunchKernelGGL(sage_kernel<0>, dim3(grid), dim3(THREADS), 0, stream,
                           h, adj, Ws, bs, Wn, bn, gamma, beta, out, N);
    }
}

// Round 12
// 25.991 us; speedup vs baseline: 1.2946x; 1.0847x over previous
//
#include <hip/hip_runtime.h>
#include <cstdint>

#define IN_F 128
#define OUT_F 128
#define NPB 8        // nodes per block
#define WAVES 16
#define THREADS 1024
#define NEG_BIG -1e30f

typedef __fp16 h2v __attribute__((ext_vector_type(2)));
union H2U { unsigned u; h2v v; };

// TN = compile-time N (1024), or 0 for runtime-generic fallback.
template<int TN>
__global__ __launch_bounds__(THREADS, 4) void sage_kernel(
    const float* __restrict__ h, const int* __restrict__ adj,
    const float* __restrict__ Ws, const float* __restrict__ bs,
    const float* __restrict__ Wn, const float* __restrict__ bn,
    const float* __restrict__ gamma, const float* __restrict__ beta,
    float* __restrict__ out, int Nrt)
{
    const int N = TN ? TN : Nrt;
    const int STRIP = N / WAVES;                 // 64 when N=1024

    // 32 KB time-shared: scanp (packed f16 partials) -> gemmp (f32 partials)
    __shared__ __align__(16) char spraw[WAVES * NPB * 64 * 4];
    auto scanp = (unsigned (*)[NPB][64])spraw;   // [WAVES][NPB][64] u32
    auto gemmp = (float (*)[NPB][OUT_F])spraw;   // [8][NPB][128] f32

    __shared__ unsigned anyw_s[WAVES];
    __shared__ float h_self[NPB][IN_F];          // 4 KB
    __shared__ float agg_s[NPB][IN_F];           // 4 KB

    const int t    = threadIdx.x;
    const int w    = t >> 6;
    const int lane = t & 63;

    const int base = blockIdx.x * NPB;
    const int b    = base / N;
    const int i0   = base - b * N;

    const float* hb   = h   + (size_t)b * N * IN_F;
    const int*   adjb = adj + (size_t)b * N * N;
    const int jbase   = w * STRIP;

    // ---- one u64 mask per node over this wave's 64-column strip ----
    unsigned long long m[NPB];
    unsigned anybits = 0;
    #pragma unroll
    for (int n = 0; n < NPB; ++n) {
        const int i_n = i0 + n;
        const int j   = jbase + lane;
        m[n] = __ballot(adjb[(size_t)i_n * N + j] != 0 && j != i_n);
        anybits |= (m[n] != 0ull ? 1u : 0u) << n;
    }

    const unsigned NEGINF2 = 0xFC00FC00u;        // (-inf,-inf) f16x2
    const unsigned POSINF2 = 0x7C007C00u;        // (+inf,+inf) f16x2

    H2U a[NPB];
    #pragma unroll
    for (int n = 0; n < NPB; ++n) a[n].u = NEGINF2;

    const float* hrow = hb + (size_t)jbase * IN_F + 2 * lane;

    if constexpr (TN == 1024) {
        // ---- fully unrolled: literal mask shifts, imm-offset load groups,
        //      fused cvt_pk -> packed f16 pk_min/pk_max (2 ops / 2 feats) ----
        #pragma unroll
        for (int g = 0; g < 8; ++g) {
            const float* p = hrow + g * 8 * IN_F;    // one base bump / 8 rows
            float2 vf[8];
            #pragma unroll
            for (int r = 0; r < 8; ++r)
                vf[r] = *(const float2*)(p + r * IN_F);  // imm offsets r*512B
            H2U vp[8];
            #pragma unroll
            for (int r = 0; r < 8; ++r)
                vp[r].v = __builtin_amdgcn_cvt_pkrtz(vf[r].x, vf[r].y); // 1 op, monotonic
            #pragma unroll
            for (int r = 0; r < 8; ++r) {
                #pragma unroll
                for (int n = 0; n < NPB; ++n) {
                    H2U cap;                       // s_bitcmp(literal)+s_cselect
                    cap.u = ((m[n] >> (g * 8 + r)) & 1ull) ? POSINF2 : NEGINF2;
                    a[n].v = __builtin_elementwise_max(a[n].v,
                                 __builtin_elementwise_min(vp[r].v, cap.v));
                }
            }
        }
    } else {
        for (int k = 0; k < STRIP; ++k) {
            const float2 vf = *(const float2*)(hrow + (size_t)k * IN_F);
            H2U vp; vp.v = __builtin_amdgcn_cvt_pkrtz(vf.x, vf.y);
            #pragma unroll
            for (int n = 0; n < NPB; ++n) {
                H2U cap; cap.u = ((m[n] >> k) & 1ull) ? POSINF2 : NEGINF2;
                a[n].v = __builtin_elementwise_max(a[n].v,
                             __builtin_elementwise_min(vp.v, cap.v));
            }
        }
    }

    #pragma unroll
    for (int n = 0; n < NPB; ++n) scanp[w][n][lane] = a[n].u;
    if (lane == 0) anyw_s[w] = anybits;
    __syncthreads();

    // ---- combine partials (waves 0-7) / stage h_self (waves 8-15) ----
    if (w < NPB) {
        H2U r; r.u = scanp[0][w][lane];
        #pragma unroll
        for (int wp = 1; wp < WAVES; ++wp) {
            H2U p; p.u = scanp[wp][w][lane];
            r.v = __builtin_elementwise_max(r.v, p.v);
        }
        unsigned anyall = 0;
        #pragma unroll
        for (int wp = 0; wp < WAVES; ++wp) anyall |= anyw_s[wp];
        float rx = (float)r.v.x;
        float ry = (float)r.v.y;
        const float2 hs = *(const float2*)&hb[(size_t)(i0 + w) * IN_F + 2 * lane];
        if (!((anyall >> w) & 1u)) { rx = hs.x; ry = hs.y; }
        *(float2*)&agg_s[w][2 * lane] = make_float2(rx, ry);
    } else {
        const int n2 = w - NPB;
        const float2 hs = *(const float2*)&hb[(size_t)(i0 + n2) * IN_F + 2 * lane];
        *(float2*)&h_self[n2][2 * lane] = hs;
    }
    __syncthreads();   // scanp consumed -> gemmp may overwrite

    // ---- GEMMs: thread (o = t&127, fc = t>>7) handles ALL 8 nodes ----
    {
        const int o  = t & (OUT_F - 1);
        const int fc = t >> 7;                   // 0..7, wave-uniform
        float acc[NPB];
        #pragma unroll
        for (int n = 0; n < NPB; ++n) acc[n] = 0.0f;

        const int f0 = fc * (IN_F / 8);          // 16 f's per chunk
        #pragma unroll
        for (int ff = 0; ff < IN_F / 8; ++ff) {
            const int f = f0 + ff;
            const float ws = Ws[f * OUT_F + o];
            const float wn = Wn[f * OUT_F + o];
            #pragma unroll
            for (int n = 0; n < NPB; ++n) {
                acc[n] = fmaf(h_self[n][f], ws, acc[n]);  // uniform LDS broadcast
                acc[n] = fmaf(agg_s[n][f],  wn, acc[n]);
            }
        }
        #pragma unroll
        for (int n = 0; n < NPB; ++n) gemmp[fc][n][o] = acc[n];
    }
    __syncthreads();

    // ---- merged reduce + bias + LayerNorm + ReLU (waves 0-7, node w) ----
    if (w < NPB) {
        float x0 = bs[lane]      + bn[lane];
        float x1 = bs[lane + 64] + bn[lane + 64];
        #pragma unroll
        for (int fcc = 0; fcc < 8; ++fcc) {
            x0 += gemmp[fcc][w][lane];
            x1 += gemmp[fcc][w][lane + 64];
        }
        float s  = x0 + x1;
        float s2 = x0 * x0 + x1 * x1;
        #pragma unroll
        for (int d = 32; d >= 1; d >>= 1) {
            s  += __shfl_xor(s, d, 64);
            s2 += __shfl_xor(s2, d, 64);
        }
        const float mu  = s * (1.0f / OUT_F);
        const float var = s2 * (1.0f / OUT_F) - mu * mu;
        const float rs  = rsqrtf(var + 1e-5f);

        float* orow = out + (size_t)(base + w) * OUT_F;
        const float r0 = (x0 - mu) * rs * gamma[lane]      + beta[lane];
        const float r1 = (x1 - mu) * rs * gamma[lane + 64] + beta[lane + 64];
        orow[lane]      = fmaxf(r0, 0.0f);
        orow[lane + 64] = fmaxf(r1, 0.0f);
    }
}

extern "C" void kernel_launch(void* const* d_in, const int* in_sizes, int n_in,
                              void* d_out, int out_size, void* d_ws, size_t ws_size,
                              hipStream_t stream) {
    const float* h     = (const float*)d_in[0];
    const int*   adj   = (const int*)d_in[1];
    const float* Ws    = (const float*)d_in[2];
    const float* bs    = (const float*)d_in[3];
    const float* Wn    = (const float*)d_in[4];
    const float* bn    = (const float*)d_in[5];
    const float* gamma = (const float*)d_in[6];
    const float* beta  = (const float*)d_in[7];
    float* out = (float*)d_out;

    const long long bn_nodes = in_sizes[0] / IN_F;          // B*N
    const int N = (int)((long long)in_sizes[1] / bn_nodes); // adj is B*N*N
    const int grid = (int)(bn_nodes / NPB);

    if (N == 1024) {
        hipLaunchKernelGGL(sage_kernel<1024>, dim3(grid), dim3(THREADS), 0, stream,
                           h, adj, Ws, bs, Wn, bn, gamma, beta, out, N);
    } else {
        hipLaunchKernelGGL(sage_kernel<0>, dim3(grid), dim3(THREADS), 0, stream,
                           h, adj, Ws, bs, Wn, bn, gamma, beta, out, N);
    }
}

// Round 13
// 24.623 us; speedup vs baseline: 1.3666x; 1.0556x over previous
//
#include <hip/hip_runtime.h>
#include <cstdint>

#define IN_F 128
#define OUT_F 128
#define NPB 8        // nodes per block
#define WAVES 16
#define THREADS 1024
#define NEG_BIG -1e30f

typedef __fp16 h2v __attribute__((ext_vector_type(2)));
union H2U { unsigned u; h2v v; };

typedef _Float16 f16x8 __attribute__((ext_vector_type(8)));
typedef float f32x4 __attribute__((ext_vector_type(4)));
union F8U { unsigned u[4]; f16x8 v; };

// TN = compile-time N (1024), or 0 for runtime-generic fallback.
template<int TN>
__global__ __launch_bounds__(THREADS, 4) void sage_kernel(
    const float* __restrict__ h, const int* __restrict__ adj,
    const float* __restrict__ Ws, const float* __restrict__ bs,
    const float* __restrict__ Wn, const float* __restrict__ bn,
    const float* __restrict__ gamma, const float* __restrict__ beta,
    float* __restrict__ out, int Nrt)
{
    const int N = TN ? TN : Nrt;
    const int STRIP = N / WAVES;                 // 64 when N=1024

    __shared__ unsigned scanp[WAVES][NPB][64];   // 32 KB scan partials (f16x2)
    __shared__ __align__(16) char Xraw[16 * 512];// 8 KB: X[n][256] f16, swizzled
    __shared__ float outp[NPB][OUT_F];           // 4 KB pre-LN outputs
    __shared__ unsigned anyw_s[WAVES];

    const int t    = threadIdx.x;
    const int w    = t >> 6;
    const int lane = t & 63;

    const int base = blockIdx.x * NPB;
    const int b    = base / N;
    const int i0   = base - b * N;

    const float* hb   = h   + (size_t)b * N * IN_F;
    const int*   adjb = adj + (size_t)b * N * N;
    const int jbase   = w * STRIP;

    // ---- one u64 mask per node over this wave's 64-column strip ----
    unsigned long long m[NPB];
    unsigned anybits = 0;
    #pragma unroll
    for (int n = 0; n < NPB; ++n) {
        const int i_n = i0 + n;
        const int j   = jbase + lane;
        m[n] = __ballot(adjb[(size_t)i_n * N + j] != 0 && j != i_n);
        anybits |= (m[n] != 0ull ? 1u : 0u) << n;
    }

    const unsigned NEGINF2 = 0xFC00FC00u;        // (-inf,-inf) f16x2
    const unsigned POSINF2 = 0x7C007C00u;        // (+inf,+inf) f16x2

    H2U a[NPB];
    #pragma unroll
    for (int n = 0; n < NPB; ++n) a[n].u = NEGINF2;

    const float* hrow = hb + (size_t)jbase * IN_F + 2 * lane;

    if constexpr (TN == 1024) {
        // ---- fully unrolled: literal mask shifts, imm-offset load groups,
        //      fused cvt_pk -> packed f16 pk_min/pk_max ----
        #pragma unroll
        for (int g = 0; g < 8; ++g) {
            const float* p = hrow + g * 8 * IN_F;    // one base bump / 8 rows
            float2 vf[8];
            #pragma unroll
            for (int r = 0; r < 8; ++r)
                vf[r] = *(const float2*)(p + r * IN_F);  // imm offsets r*512B
            H2U vp[8];
            #pragma unroll
            for (int r = 0; r < 8; ++r)
                vp[r].v = __builtin_amdgcn_cvt_pkrtz(vf[r].x, vf[r].y);
            #pragma unroll
            for (int r = 0; r < 8; ++r) {
                #pragma unroll
                for (int n = 0; n < NPB; ++n) {
                    H2U cap;                       // s_bitcmp(literal)+s_cselect
                    cap.u = ((m[n] >> (g * 8 + r)) & 1ull) ? POSINF2 : NEGINF2;
                    a[n].v = __builtin_elementwise_max(a[n].v,
                                 __builtin_elementwise_min(vp[r].v, cap.v));
                }
            }
        }
    } else {
        for (int k = 0; k < STRIP; ++k) {
            const float2 vf = *(const float2*)(hrow + (size_t)k * IN_F);
            H2U vp; vp.v = __builtin_amdgcn_cvt_pkrtz(vf.x, vf.y);
            #pragma unroll
            for (int n = 0; n < NPB; ++n) {
                H2U cap; cap.u = ((m[n] >> k) & 1ull) ? POSINF2 : NEGINF2;
                a[n].v = __builtin_elementwise_max(a[n].v,
                             __builtin_elementwise_min(vp.v, cap.v));
            }
        }
    }

    #pragma unroll
    for (int n = 0; n < NPB; ++n) scanp[w][n][lane] = a[n].u;
    if (lane == 0) anyw_s[w] = anybits;
    __syncthreads();

    // ---- combine partials -> X agg half (waves 0-7); X self half (8-15) ----
    // X[n][k] f16, row = 512 B, byte offsets XOR-swizzled by ((n&7)<<4).
    if (w < NPB) {
        H2U r; r.u = scanp[0][w][lane];
        #pragma unroll
        for (int wp = 1; wp < WAVES; ++wp) {
            H2U p; p.u = scanp[wp][w][lane];
            r.v = __builtin_elementwise_max(r.v, p.v);
        }
        unsigned anyall = 0;
        #pragma unroll
        for (int wp = 0; wp < WAVES; ++wp) anyall |= anyw_s[wp];
        if (!((anyall >> w) & 1u)) {   // no neighbors -> self features
            const float2 hs = *(const float2*)&hb[(size_t)(i0 + w) * IN_F + 2 * lane];
            r.v = __builtin_amdgcn_cvt_pkrtz(hs.x, hs.y);
        }
        const unsigned byte = (unsigned)(w * 512 + 256 + lane * 4) ^ ((w & 7) << 4);
        *(unsigned*)(Xraw + byte) = r.u;
    } else {
        const int n2 = w - NPB;
        const float2 hs = *(const float2*)&hb[(size_t)(i0 + n2) * IN_F + 2 * lane];
        H2U p; p.v = __builtin_amdgcn_cvt_pkrtz(hs.x, hs.y);
        const unsigned byte = (unsigned)(n2 * 512 + lane * 4) ^ ((n2 & 7) << 4);
        *(unsigned*)(Xraw + byte) = p.u;
    }
    __syncthreads();

    // ---- MFMA epilogue: out(8x128) = X(8x256,f16) . [Ws;Wn](256x128,f16) ----
    // Wave w<8 owns o-tile [w*16, w*16+16). D = A.B: A[r][k]=W[k][w*16+r],
    // B[k][c]=X[c][k]. Lane: r/c = lane&15, k-group = lane>>4 (8 k's each).
    if (w < NPB) {
        const int col = lane & 15;
        const int kg  = lane >> 4;
        f32x4 acc = {0.f, 0.f, 0.f, 0.f};
        #pragma unroll
        for (int chunk = 0; chunk < 8; ++chunk) {
            const float* Wsrc = (chunk < 4) ? Ws : Wn;
            const int kbase = (chunk & 3) * 32 + kg * 8;
            float wv[8];
            #pragma unroll
            for (int j = 0; j < 8; ++j)
                wv[j] = Wsrc[(kbase + j) * OUT_F + w * 16 + col];
            F8U af;
            #pragma unroll
            for (int j2 = 0; j2 < 4; ++j2) {
                H2U pk; pk.v = __builtin_amdgcn_cvt_pkrtz(wv[2 * j2], wv[2 * j2 + 1]);
                af.u[j2] = pk.u;
            }
            const unsigned byte = (unsigned)(col * 512 + chunk * 64 + kg * 16) ^ ((col & 7) << 4);
            const uint4 braw = *(const uint4*)(Xraw + byte);
            F8U bf; bf.u[0] = braw.x; bf.u[1] = braw.y; bf.u[2] = braw.z; bf.u[3] = braw.w;
            acc = __builtin_amdgcn_mfma_f32_16x16x32_f16(af.v, bf.v, acc, 0, 0, 0);
        }
        if (col < NPB) {   // D[row=kg*4+q][col] = out[node col][o = w*16+kg*4+q]
            #pragma unroll
            for (int q = 0; q < 4; ++q)
                outp[col][w * 16 + kg * 4 + q] = acc[q];
        }
    }
    __syncthreads();

    // ---- bias + LayerNorm + ReLU (waves 0-7, node w) ----
    if (w < NPB) {
        float x0 = bs[lane]      + bn[lane]      + outp[w][lane];
        float x1 = bs[lane + 64] + bn[lane + 64] + outp[w][lane + 64];
        float s  = x0 + x1;
        float s2 = x0 * x0 + x1 * x1;
        #pragma unroll
        for (int d = 32; d >= 1; d >>= 1) {
            s  += __shfl_xor(s, d, 64);
            s2 += __shfl_xor(s2, d, 64);
        }
        const float mu  = s * (1.0f / OUT_F);
        const float var = s2 * (1.0f / OUT_F) - mu * mu;
        const float rs  = rsqrtf(var + 1e-5f);

        float* orow = out + (size_t)(base + w) * OUT_F;
        const float r0 = (x0 - mu) * rs * gamma[lane]      + beta[lane];
        const float r1 = (x1 - mu) * rs * gamma[lane + 64] + beta[lane + 64];
        orow[lane]      = fmaxf(r0, 0.0f);
        orow[lane + 64] = fmaxf(r1, 0.0f);
    }
}

extern "C" void kernel_launch(void* const* d_in, const int* in_sizes, int n_in,
                              void* d_out, int out_size, void* d_ws, size_t ws_size,
                              hipStream_t stream) {
    const float* h     = (const float*)d_in[0];
    const int*   adj   = (const int*)d_in[1];
    const float* Ws    = (const float*)d_in[2];
    const float* bs    = (const float*)d_in[3];
    const float* Wn    = (const float*)d_in[4];
    const float* bn    = (const float*)d_in[5];
    const float* gamma = (const float*)d_in[6];
    const float* beta  = (const float*)d_in[7];
    float* out = (float*)d_out;

    const long long bn_nodes = in_sizes[0] / IN_F;          // B*N
    const int N = (int)((long long)in_sizes[1] / bn_nodes); // adj is B*N*N
    const int grid = (int)(bn_nodes / NPB);

    if (N == 1024) {
        hipLaunchKernelGGL(sage_kernel<1024>, dim3(grid), dim3(THREADS), 0, stream,
                           h, adj, Ws, bs, Wn, bn, gamma, beta, out, N);
    } else {
        hipLaunchKernelGGL(sage_kernel<0>, dim3(grid), dim3(THREADS), 0, stream,
                           h, adj, Ws, bs, Wn, bn, gamma, beta, out, N);
    }
}